// Round 16
// baseline (344.696 us; speedup 1.0000x reference)
//
#include <hip/hip_runtime.h>
#include <hip/hip_bf16.h>

typedef unsigned short ushort_t;
typedef unsigned char uchar_t;
typedef __attribute__((ext_vector_type(4))) int int4v;
typedef __attribute__((ext_vector_type(2))) unsigned int uint2v;

#define NQ      2048
#define ND      512
#define NDB     100000
#define TOPK    10
#define NCHUNK  98
#define CHUNK_N 1024                  // 8 tiles * 128
#define NPAD    (NCHUNK * CHUNK_N)    // 100352 >= 100000
#define QTILES  (NQ / 128)            // 16
#define NTILES  (CHUNK_N / 128)       // 8
#define NWG     (NCHUNK * QTILES)     // 1568 = 8 * 196
#define PERXCD  (NWG / 8)             // 196
#define QSCALE  400.0f
#define QINV    (1.0f / (QSCALE * QSCALE))
#define IMIN    (-2147483647 - 1)

// async global->LDS, 16B per lane, wave-uniform LDS base + lane*16
#define GL2LDS(gp, lp) __builtin_amdgcn_global_load_lds(                      \
    (const __attribute__((address_space(1))) void*)(gp),                     \
    (__attribute__((address_space(3))) void*)(lp), 16, 0, 0)

// ---------- row L2-normalize, fp32 -> i8 (x*400, RNE, clamp +-127); zero pad rows ----------
__global__ void normalize_rows_i8(const float* __restrict__ in, uchar_t* __restrict__ out,
                                  int nvalid, int ntotal) {
    int row  = blockIdx.x * 4 + (threadIdx.x >> 6);
    int lane = threadIdx.x & 63;
    if (row >= ntotal) return;
    uint2v pk;
    if (row >= nvalid) {
        pk[0] = 0u; pk[1] = 0u;
    } else {
        const float4* src = reinterpret_cast<const float4*>(in + (size_t)row * ND);
        float4 v0 = src[lane * 2];
        float4 v1 = src[lane * 2 + 1];
        float s = v0.x*v0.x + v0.y*v0.y + v0.z*v0.z + v0.w*v0.w
                + v1.x*v1.x + v1.y*v1.y + v1.z*v1.z + v1.w*v1.w;
        #pragma unroll
        for (int off = 32; off; off >>= 1) s += __shfl_xor(s, off, 64);
        float r = rsqrtf(s) * QSCALE;
        float f[8] = { v0.x, v0.y, v0.z, v0.w, v1.x, v1.y, v1.z, v1.w };
        unsigned b[8];
        #pragma unroll
        for (int i = 0; i < 8; ++i) {
            int q = (int)rintf(f[i] * r);
            q = q > 127 ? 127 : (q < -127 ? -127 : q);
            b[i] = (unsigned)q & 0xFFu;
        }
        pk[0] = b[0] | (b[1] << 8) | (b[2] << 16) | (b[3] << 24);
        pk[1] = b[4] | (b[5] << 8) | (b[6] << 16) | (b[7] << 24);
    }
    *reinterpret_cast<uint2v*>(out + (size_t)row * ND + lane * 8) = pk;
}

__device__ inline void topk_insert_i(int (&top)[TOPK], int x) {
    #pragma unroll
    for (int i = 0; i < TOPK; ++i) {
        int mx = top[i] > x ? top[i] : x;
        int mn = top[i] > x ? x : top[i];
        top[i] = mx;
        x = mn;
    }
}

// ---------- fused i8 GEMM + per-chunk top-10: R15 + double-buffer + counted waits ----------
// 512 threads, 8 waves; wave wv owns queries [wv*16, +16) x all 128 n of the tile.
// A,B double-buffered (2 x 8 KB each, 32 KB LDS). Per K-step:
//   s_waitcnt vmcnt(0)   <- drains stage issued ONE FULL PHASE ago (cheap)
//   s_barrier            <- after own-vmcnt(0): ALL waves' chunks landed (cross-wave safe)
//   issue stage(ks+1)    <- flies during this step's reads+MFMA and selection
//   9 ds_read_b128 + 8 MFMA from buf[ks&1]
// One barrier per K-step (R15 had two + zero-overlap stage).
__global__ __launch_bounds__(512, 8)
void knn_chunk(const uchar_t* __restrict__ qb, const uchar_t* __restrict__ dbb,
               int* __restrict__ partial) {
    // XCD swizzle: 16 consecutive logicals (same B-chunk) land on the same XCD
    const int logical = (blockIdx.x & 7) * PERXCD + (blockIdx.x >> 3);
    const int qt = logical & (QTILES - 1);
    const int nc = logical >> 4;       // QTILES == 16
    const int t = threadIdx.x, lane = t & 63, wv = t >> 6;
    const int l15 = lane & 15;

    __shared__ __align__(16) uchar_t As[2][128 * 64];    // 16 KB
    __shared__ __align__(16) uchar_t Bs[2][128 * 64];    // 16 KB

    int top[TOPK];
    #pragma unroll
    for (int i = 0; i < TOPK; ++i) top[i] = IMIN;

    const size_t nchunkbase = (size_t)nc * CHUNK_N;
    const uchar_t* aseg = qb + (size_t)(qt * 128) * ND;

    // ---- hoisted per-lane invariants (identical to R15) ----
    const int srow = t >> 2;
    const int scol = (t & 3) ^ ((srow >> 1) & 3);       // inverse swizzle on global source
    const int soff = srow * ND + scol * 16;
    const int doff = t * 16;
    const int cgrp = lane >> 4;                          // logical 16B chunk in row
    const int slot = (cgrp ^ ((l15 >> 1) & 3)) * 16;
    const int aoff = (wv * 16 + l15) * 64 + slot;        // A row = wv*16 + l15
    const int boff = l15 * 64 + slot;                    // B row = ns*16 + l15 (ns via imm)

    // prologue: stage (nt=0, ks=0) into buffer 0
    {
        const uchar_t* bseg0 = dbb + nchunkbase * ND;
        GL2LDS(aseg + soff, As[0] + doff);
        GL2LDS(bseg0 + soff, Bs[0] + doff);
    }

    for (int nt = 0; nt < NTILES; ++nt) {
        const uchar_t* bseg = dbb + (nchunkbase + nt * 128) * ND;
        int4v acc[8];
        #pragma unroll
        for (int b = 0; b < 8; ++b) acc[b] = (int4v){0, 0, 0, 0};

        #pragma unroll
        for (int ks = 0; ks < 8; ++ks) {
            // drain own stage(ks) (issued one full phase ago), then cross-wave barrier
            asm volatile("s_waitcnt vmcnt(0)" ::: "memory");
            __builtin_amdgcn_s_barrier();
            asm volatile("" ::: "memory");       // no LDS reads hoist above the barrier

            // issue stage(ks+1) into the other buffer; lands during compute+selection
            if (ks < 7) {
                GL2LDS(aseg + soff + (ks + 1) * 64, As[(ks + 1) & 1] + doff);
                GL2LDS(bseg + soff + (ks + 1) * 64, Bs[(ks + 1) & 1] + doff);
            } else if (nt + 1 < NTILES) {
                GL2LDS(aseg + soff, As[0] + doff);
                GL2LDS(bseg + 128 * ND + soff, Bs[0] + doff);
            }

            const uchar_t* Ac = As[ks & 1];
            const uchar_t* Bc = Bs[ks & 1];
            int4v af = *reinterpret_cast<const int4v*>(Ac + aoff);
            {
                int4v bf0 = *reinterpret_cast<const int4v*>(Bc + boff);
                int4v bf1 = *reinterpret_cast<const int4v*>(Bc + boff + 1024);
                int4v bf2 = *reinterpret_cast<const int4v*>(Bc + boff + 2048);
                int4v bf3 = *reinterpret_cast<const int4v*>(Bc + boff + 3072);
                acc[0] = __builtin_amdgcn_mfma_i32_16x16x64_i8(bf0, af, acc[0], 0, 0, 0);
                acc[1] = __builtin_amdgcn_mfma_i32_16x16x64_i8(bf1, af, acc[1], 0, 0, 0);
                acc[2] = __builtin_amdgcn_mfma_i32_16x16x64_i8(bf2, af, acc[2], 0, 0, 0);
                acc[3] = __builtin_amdgcn_mfma_i32_16x16x64_i8(bf3, af, acc[3], 0, 0, 0);
            }
            {
                int4v bf4 = *reinterpret_cast<const int4v*>(Bc + boff + 4096);
                int4v bf5 = *reinterpret_cast<const int4v*>(Bc + boff + 5120);
                int4v bf6 = *reinterpret_cast<const int4v*>(Bc + boff + 6144);
                int4v bf7 = *reinterpret_cast<const int4v*>(Bc + boff + 7168);
                acc[4] = __builtin_amdgcn_mfma_i32_16x16x64_i8(bf4, af, acc[4], 0, 0, 0);
                acc[5] = __builtin_amdgcn_mfma_i32_16x16x64_i8(bf5, af, acc[5], 0, 0, 0);
                acc[6] = __builtin_amdgcn_mfma_i32_16x16x64_i8(bf6, af, acc[6], 0, 0, 0);
                acc[7] = __builtin_amdgcn_mfma_i32_16x16x64_i8(bf7, af, acc[7], 0, 0, 0);
            }
        }

        // integer selection (32 candidates, single query); next stage is in flight
        int m = acc[0][0];
        #pragma unroll
        for (int ns = 0; ns < 8; ++ns)
            #pragma unroll
            for (int r = 0; r < 4; ++r)
                m = m > acc[ns][r] ? m : acc[ns][r];
        if (m > top[TOPK - 1]) {
            #pragma unroll
            for (int ns = 0; ns < 8; ++ns)
                #pragma unroll
                for (int r = 0; r < 4; ++r) {
                    int v = acc[ns][r];
                    if (v > top[TOPK - 1]) topk_insert_i(top, v);
                }
        }
    }

    // butterfly merge across the 4 lanes sharing each query (lane ^ 16, lane ^ 32)
    #pragma unroll
    for (int step = 16; step <= 32; step <<= 1) {
        int other[TOPK];
        #pragma unroll
        for (int i = 0; i < TOPK; ++i) other[i] = __shfl_xor(top[i], step, 64);
        #pragma unroll
        for (int i = 0; i < TOPK; ++i)
            if (other[i] > top[TOPK - 1]) topk_insert_i(top, other[i]);
    }

    // lanes 0..15 hold the final per-query top-10 for q = qt*128 + wv*16 + l15
    if ((lane >> 4) == 0) {
        const int q = qt * 128 + wv * 16 + l15;
        int* dst = partial + ((size_t)nc * NQ + q) * TOPK;
        #pragma unroll
        for (int i = 0; i < TOPK; ++i) dst[i] = top[i];
    }
}

// ---------- merge NCHUNK chunks per query (int domain), emit k-th squared distance ----------
__global__ void final_merge(const int* __restrict__ partial, float* __restrict__ out) {
    const int q = blockIdx.x * 4 + (threadIdx.x >> 6);
    const int lane = threadIdx.x & 63;
    if (q >= NQ) return;
    int top[TOPK];
    #pragma unroll
    for (int i = 0; i < TOPK; ++i) top[i] = IMIN;
    for (int c = lane; c < NCHUNK; c += 64) {
        const int* p = partial + ((size_t)c * NQ + q) * TOPK;
        #pragma unroll
        for (int i = 0; i < TOPK; ++i) {
            int x = p[i];
            if (x > top[TOPK - 1]) topk_insert_i(top, x);
        }
    }
    #pragma unroll
    for (int step = 1; step <= 32; step <<= 1) {
        int other[TOPK];
        #pragma unroll
        for (int i = 0; i < TOPK; ++i) other[i] = __shfl_xor(top[i], step, 64);
        #pragma unroll
        for (int i = 0; i < TOPK; ++i)
            if (other[i] > top[TOPK - 1]) topk_insert_i(top, other[i]);
    }
    if (lane == 0) out[q] = 2.0f - 2.0f * ((float)top[TOPK - 1] * QINV);
}

extern "C" void kernel_launch(void* const* d_in, const int* in_sizes, int n_in,
                              void* d_out, int out_size, void* d_ws, size_t ws_size,
                              hipStream_t stream) {
    const float* features = (const float*)d_in[0];
    const float* dbf      = (const float*)d_in[2];
    float* out = (float*)d_out;

    uchar_t* dbb = (uchar_t*)d_ws;                           // [NPAD][512] i8     ~51.4 MB
    uchar_t* qbn = dbb + (size_t)NPAD * ND;                  // [2048][512] i8     ~1 MB
    int* partial = (int*)(qbn + (size_t)NQ * ND);            // [NCHUNK][2048][10] ~8.0 MB

    normalize_rows_i8<<<NPAD / 4, 256, 0, stream>>>(dbf, dbb, NDB, NPAD);
    normalize_rows_i8<<<NQ / 4, 256, 0, stream>>>(features, qbn, NQ, NQ);
    knn_chunk<<<NWG, 512, 0, stream>>>(qbn, dbb, partial);
    final_merge<<<NQ / 4, 256, 0, stream>>>(partial, out);
}